// Round 1
// 766.787 us; speedup vs baseline: 1.0982x; 1.0982x over previous
//
#include <hip/hip_runtime.h>
#include <hip/hip_bf16.h>

#define DIM 384
#define DI 768
#define S_LEN 1024
#define NB 32
#define M_ROWS (NB * S_LEN)   // 32768
#define MLP_DIM 1536
#define CHUNKS 32
#define CLEN (S_LEN / CHUNKS)  // 32

typedef __bf16 bf16x8 __attribute__((ext_vector_type(8)));
typedef float f32x4 __attribute__((ext_vector_type(4)));

#define GLOBAL_AS __attribute__((address_space(1)))
#define LDS_AS __attribute__((address_space(3)))

// ---------------- LayerNorm: one wave per row of 384 ----------------
template <typename OutT>
__global__ __launch_bounds__(256) void ln_kernel(const float* __restrict__ x,
                                                 const float* __restrict__ gamma,
                                                 const float* __restrict__ beta,
                                                 OutT* __restrict__ out) {
    int row = blockIdx.x * 4 + (threadIdx.x >> 6);
    int lane = threadIdx.x & 63;
    const float* xr = x + (size_t)row * DIM;
    float v[6];
    float s = 0.f, sq = 0.f;
#pragma unroll
    for (int i = 0; i < 6; ++i) {
        v[i] = xr[lane + i * 64];
        s += v[i];
        sq += v[i] * v[i];
    }
#pragma unroll
    for (int off = 32; off > 0; off >>= 1) {
        s += __shfl_down(s, off);
        sq += __shfl_down(sq, off);
    }
    s = __shfl(s, 0);
    sq = __shfl(sq, 0);
    float mean = s * (1.f / DIM);
    float var = sq * (1.f / DIM) - mean * mean;
    float rstd = rsqrtf(var + 1e-5f);
    OutT* orow = out + (size_t)row * DIM;
#pragma unroll
    for (int i = 0; i < 6; ++i) {
        int c = lane + i * 64;
        float y = (v[i] - mean) * rstd * gamma[c] + beta[c];
        if constexpr (sizeof(OutT) == 2)
            orow[c] = __float2bfloat16(y);
        else
            orow[c] = y;
    }
}

// ---------------- Depthwise 3x3 conv (channel-last, bf16 in), +bias, -> bf16 ----------------
__global__ __launch_bounds__(256) void dwconv_kernel(const __hip_bfloat16* __restrict__ xn,
                                                     const float* __restrict__ w,
                                                     const float* __restrict__ b,
                                                     __hip_bfloat16* __restrict__ xs) {
    size_t idx = (size_t)blockIdx.x * 256 + threadIdx.x;
    int c = (int)(idx % DIM);
    int s = (int)((idx / DIM) % S_LEN);
    int n = (int)(idx / ((size_t)DIM * S_LEN));
    int h0 = s >> 5, w0 = s & 31;
    float acc = b[c];
#pragma unroll
    for (int kh = 0; kh < 3; ++kh) {
        int hh = h0 + kh - 1;
        if (hh < 0 || hh > 31) continue;
#pragma unroll
        for (int kw = 0; kw < 3; ++kw) {
            int ww = w0 + kw - 1;
            if (ww < 0 || ww > 31) continue;
            acc += __bfloat162float(xn[((size_t)n * S_LEN + hh * 32 + ww) * DIM + c]) * w[c * 9 + kh * 3 + kw];
        }
    }
    xs[idx] = __float2bfloat16(acc);
}

// ------- transpose + cast f32 -> bf16: out[c*ostride + ooff + r] = in[r*C + c] -------
__global__ __launch_bounds__(256) void transpose_bf16_kernel(const float* __restrict__ in,
                                                             __hip_bfloat16* __restrict__ out,
                                                             int R, int C, int ostride, int ooff) {
    int idx = blockIdx.x * 256 + threadIdx.x;
    if (idx >= R * C) return;
    int r = idx / C, c = idx % C;
    out[(size_t)c * ostride + ooff + r] = __float2bfloat16(in[idx]);
}

// ---------------- minGRU chunked scan ----------------
__device__ __forceinline__ void gru_ab(float hid, float gate, float& a, float& bv) {
    float z = 1.f / (1.f + __expf(-gate));
    float gh = (hid >= 0.f) ? (hid + 0.5f) : (1.f / (1.f + __expf(-hid)));
    a = 1.f - z;
    bv = z * gh;
}

__global__ __launch_bounds__(256) void scan_part1(const __hip_bfloat16* __restrict__ hg,
                                                  float* __restrict__ summ, int rev) {
    int tid = blockIdx.x * 256 + threadIdx.x;  // NB*CHUNKS*DI
    int c = tid % DI;
    int j = (tid / DI) % CHUNKS;
    int b = tid / (DI * CHUNKS);
    const __hip_bfloat16* base = hg + (size_t)b * S_LEN * (2 * DI);
    float A = 1.f, Bv = 0.f;
    for (int i = 0; i < CLEN; i += 8) {
        float hid[8], gate[8];
#pragma unroll
        for (int q = 0; q < 8; ++q) {
            int pos = j * CLEN + i + q;
            int t = rev ? (S_LEN - 1 - pos) : pos;
            hid[q] = __bfloat162float(base[(size_t)t * (2 * DI) + c]);
            gate[q] = __bfloat162float(base[(size_t)t * (2 * DI) + DI + c]);
        }
#pragma unroll
        for (int q = 0; q < 8; ++q) {
            float a, bv;
            gru_ab(hid[q], gate[q], a, bv);
            A *= a;
            Bv = a * Bv + bv;
        }
    }
    int idx = (j * NB + b) * DI + c;
    summ[idx] = A;
    summ[(size_t)CHUNKS * NB * DI + idx] = Bv;
}

// part2: writes h with row stride `ostride`; may alias hg in-place (1:1 read-before-write)
__global__ __launch_bounds__(256) void scan_part2(const __hip_bfloat16* __restrict__ hg,
                                                  const float* __restrict__ summ,
                                                  __hip_bfloat16* __restrict__ ho, int rev,
                                                  int ostride) {
    int tid = blockIdx.x * 256 + threadIdx.x;
    int c = tid % DI;
    int j = (tid / DI) % CHUNKS;
    int b = tid / (DI * CHUNKS);
    const float* sB = summ + (size_t)CHUNKS * NB * DI;
    float h = 0.f;
    for (int jp = 0; jp < j; ++jp) {
        int idx = (jp * NB + b) * DI + c;
        h = summ[idx] * h + sB[idx];
    }
    const __hip_bfloat16* base = hg + (size_t)b * S_LEN * (2 * DI);
    __hip_bfloat16* hob = ho + (size_t)b * S_LEN * ostride;
    for (int i = 0; i < CLEN; i += 8) {
        float hid[8], gate[8];
        int tt[8];
#pragma unroll
        for (int q = 0; q < 8; ++q) {
            int pos = j * CLEN + i + q;
            int t = rev ? (S_LEN - 1 - pos) : pos;
            tt[q] = t;
            hid[q] = __bfloat162float(base[(size_t)t * (2 * DI) + c]);
            gate[q] = __bfloat162float(base[(size_t)t * (2 * DI) + DI + c]);
        }
#pragma unroll
        for (int q = 0; q < 8; ++q) {
            float a, bv;
            gru_ab(hid[q], gate[q], a, bv);
            h = a * h + bv;
            hob[(size_t)tt[q] * ostride + c] = __float2bfloat16(h);
        }
    }
}

// ------- bf16 MFMA GEMM: dual-A (k-split), global_load_lds staging, depth-2 prefetch -------
// out = [A1|A2](MxK) @ B(KxN); Bt is N x K. MFMA as (b,a): lane -> row m (lr), 4 consecutive cols.
// Pipeline: 3 LDS buffers, stage(t+2) at top of iter t, counted s_waitcnt vmcnt(8) before the
// producer barrier (loads for t+1/t+2 stay in flight across it). lgkmcnt(0)+barrier after the
// MFMAs fences the WAR: stage(t+2) overwrites buf[(t-1)%3], last read in iter t-1.
// XCD-chunked tile swizzle: blocks sharing an A-panel land on one XCD's L2 (all grids %8==0).
__global__ __launch_bounds__(256) void gemm_bt(const __hip_bfloat16* __restrict__ A1, int lda1,
                                               const __hip_bfloat16* __restrict__ A2, int lda2,
                                               int ksplit,
                                               const __hip_bfloat16* __restrict__ Bt,
                                               int M, int N, int K,
                                               __hip_bfloat16* __restrict__ outH,
                                               float* __restrict__ outF,
                                               const float* __restrict__ bias,
                                               const float* __restrict__ add,
                                               int act) {
    __shared__ __align__(16) __hip_bfloat16 sA[3][128 * 32];
    __shared__ __align__(16) __hip_bfloat16 sB[3][128 * 32];
    int t = threadIdx.x;

    // XCD swizzle: hardware round-robins consecutive block ids across 8 XCDs; remap so each
    // XCD processes a contiguous chunk of tiles (contiguous M-panels -> A panel fits its L2).
    int nwg = gridDim.x * gridDim.y;
    int bid = blockIdx.y * gridDim.x + blockIdx.x;
    int cpx = nwg >> 3;  // all gemm grids here are divisible by 8 (bijective)
    int tile = (bid & 7) * cpx + (bid >> 3);
    int bx = tile % gridDim.x;
    int by = tile / gridDim.x;
    int n0 = bx * 128;
    int m0 = by * 128;

    int wave = t >> 6, lane = t & 63;
    int wm = (wave >> 1) << 6, wn = (wave & 1) << 6;
    int quad = lane >> 4, lr = lane & 15;

    f32x4 acc[4][4];
#pragma unroll
    for (int i = 0; i < 4; ++i)
#pragma unroll
        for (int j = 0; j < 4; ++j)
#pragma unroll
            for (int e = 0; e < 4; ++e) acc[i][j][e] = 0.f;

    int ch0 = wave * 128 + lane;
    int ch1 = wave * 128 + 64 + lane;
    int r0 = ch0 >> 2, g0 = (ch0 & 3) * 8;
    int r1 = ch1 >> 2, g1 = (ch1 & 3) * 8;

    const int KT = K >> 5;  // #32-wide k-tiles (>= 12 for all calls)

    auto stage = [&](int kt) {
        int k0 = kt << 5;
        const __hip_bfloat16* Ab;
        int ldx, kk;
        if (k0 < ksplit) { Ab = A1; ldx = lda1; kk = k0; }
        else             { Ab = A2; ldx = lda2; kk = k0 - ksplit; }
        int bi = kt % 3;
        __builtin_amdgcn_global_load_lds((const GLOBAL_AS void*)(Ab + (size_t)(m0 + r0) * ldx + kk + g0),
                                         (LDS_AS void*)&sA[bi][ch0 * 8], 16, 0, 0);
        __builtin_amdgcn_global_load_lds((const GLOBAL_AS void*)(Ab + (size_t)(m0 + r1) * ldx + kk + g1),
                                         (LDS_AS void*)&sA[bi][ch1 * 8], 16, 0, 0);
        __builtin_amdgcn_global_load_lds((const GLOBAL_AS void*)(Bt + (size_t)(n0 + r0) * K + k0 + g0),
                                         (LDS_AS void*)&sB[bi][ch0 * 8], 16, 0, 0);
        __builtin_amdgcn_global_load_lds((const GLOBAL_AS void*)(Bt + (size_t)(n0 + r1) * K + k0 + g1),
                                         (LDS_AS void*)&sB[bi][ch1 * 8], 16, 0, 0);
    };

    stage(0);
    stage(1);
    for (int kt = 0; kt < KT; ++kt) {
        if (kt + 2 < KT) {
            stage(kt + 2);
            // 12 loads may be outstanding; keep the 8 newest (tiles kt+1, kt+2) in flight.
            asm volatile("s_waitcnt vmcnt(8)" ::: "memory");
        } else if (kt + 2 == KT) {
            asm volatile("s_waitcnt vmcnt(4)" ::: "memory");
        } else {
            asm volatile("s_waitcnt vmcnt(0)" ::: "memory");
        }
        __builtin_amdgcn_s_barrier();  // buf[kt%3] ready for all waves
        int bi = kt % 3;
        bf16x8 af[4], bfr[4];
#pragma unroll
        for (int mi = 0; mi < 4; ++mi)
            af[mi] = *(const bf16x8*)&sA[bi][(wm + mi * 16 + lr) * 32 + quad * 8];
#pragma unroll
        for (int ni = 0; ni < 4; ++ni)
            bfr[ni] = *(const bf16x8*)&sB[bi][(wn + ni * 16 + lr) * 32 + quad * 8];
#pragma unroll
        for (int mi = 0; mi < 4; ++mi)
#pragma unroll
            for (int ni = 0; ni < 4; ++ni)
                acc[mi][ni] = __builtin_amdgcn_mfma_f32_16x16x32_bf16(bfr[ni], af[mi], acc[mi][ni], 0, 0, 0);
        // All ds_reads of buf[kt%3] must land before any wave's stage(kt+3) overwrites it.
        asm volatile("s_waitcnt lgkmcnt(0)" ::: "memory");
        __builtin_amdgcn_s_barrier();
    }

    // epilogue: row = m0+wm+mi*16+lr, cols = n0+wn+ni*16+quad*4 .. +3 (plain stores; L2 merges)
#pragma unroll
    for (int mi = 0; mi < 4; ++mi) {
        int row = m0 + wm + mi * 16 + lr;
#pragma unroll
        for (int ni = 0; ni < 4; ++ni) {
            int col = n0 + wn + ni * 16 + quad * 4;
            size_t idx = (size_t)row * N + col;
            f32x4 v = acc[mi][ni];
            if (bias) {
                const float4 b4 = *(const float4*)&bias[col];
                v[0] += b4.x; v[1] += b4.y; v[2] += b4.z; v[3] += b4.w;
            }
            if (act == 1) {
#pragma unroll
                for (int e = 0; e < 4; ++e) {
                    // tanh-approx gelu (max dev ~3e-4 vs exact; vanishes through next GEMM)
                    float xv = v[e];
                    float u = 0.7978845608f * (xv + 0.044715f * xv * xv * xv);
                    float ex = __expf(2.f * u);
                    float th = (ex - 1.f) / (ex + 1.f);
                    v[e] = 0.5f * xv * (1.f + th);
                }
            }
            if (add) {
                const float4 a4 = *(const float4*)&add[idx];
                v[0] += a4.x; v[1] += a4.y; v[2] += a4.z; v[3] += a4.w;
            }
            if (outH) {
                union { __hip_bfloat16 h[4]; int2 i2; } u;
                u.h[0] = __float2bfloat16(v[0]);
                u.h[1] = __float2bfloat16(v[1]);
                u.h[2] = __float2bfloat16(v[2]);
                u.h[3] = __float2bfloat16(v[3]);
                *(int2*)&outH[idx] = u.i2;
            } else {
                *(float4*)&outF[idx] = make_float4(v[0], v[1], v[2], v[3]);
            }
        }
    }
}

extern "C" void kernel_launch(void* const* d_in, const int* in_sizes, int n_in,
                              void* d_out, int out_size, void* d_ws, size_t ws_size,
                              hipStream_t stream) {
    const float* x = (const float*)d_in[0];
    const float* gamma1 = (const float*)d_in[1];
    const float* beta1 = (const float*)d_in[2];
    const float* dwc_w = (const float*)d_in[3];
    const float* dwc_b = (const float*)d_in[4];
    const float* gru1_w = (const float*)d_in[5];
    const float* gru1_o = (const float*)d_in[6];
    const float* gru2_w = (const float*)d_in[7];
    const float* gru2_o = (const float*)d_in[8];
    const float* gamma2 = (const float*)d_in[9];
    const float* beta2 = (const float*)d_in[10];
    const float* p1_w = (const float*)d_in[11];
    const float* p1_b = (const float*)d_in[12];
    const float* p2_w = (const float*)d_in[13];
    const float* p2_b = (const float*)d_in[14];
    float* out = (float*)d_out;

    char* ws = (char*)d_ws;
    size_t off = 0;
    auto alloc = [&](size_t b) {
        char* p = ws + off;
        off += (b + 255) & ~(size_t)255;
        return p;
    };
    const size_t M = M_ROWS;
    // ws total ~188 MB
    __hip_bfloat16* hg = (__hip_bfloat16*)alloc(M * 2 * DI * 2);    // 100.7 MB; h2 in-place; later t1
    __hip_bfloat16* hbuf = (__hip_bfloat16*)alloc(M * DI * 2);      // 50.3 MB: LN1-bf16 out, then h1
    __hip_bfloat16* xs = (__hip_bfloat16*)alloc(M * DIM * 2);       // 25.2 MB; later yn
    float* summ = (float*)alloc((size_t)2 * CHUNKS * NB * DI * 4);  // 6.3 MB
    __hip_bfloat16* w1T = (__hip_bfloat16*)alloc((size_t)DIM * 2 * DI * 2);
    __hip_bfloat16* w2T = (__hip_bfloat16*)alloc((size_t)DIM * 2 * DI * 2);
    __hip_bfloat16* ocT = (__hip_bfloat16*)alloc((size_t)DIM * 2 * DI * 2);  // 384 x 1536 = [o1;o2]^T
    __hip_bfloat16* p1T = (__hip_bfloat16*)alloc((size_t)DIM * MLP_DIM * 2);
    __hip_bfloat16* p2T = (__hip_bfloat16*)alloc((size_t)MLP_DIM * DIM * 2);
    __hip_bfloat16* xnb = hbuf;           // LN1 out (bf16); dead after dwconv, before scan1
    float* y = (float*)d_out;             // post-GRU residual; same-idx RMW only
    __hip_bfloat16* yn = xs;              // LN2 out; xs dead after GRU2 input GEMM
    __hip_bfloat16* t1 = hg;              // MLP hidden; hg dead after scan2

    auto tgrid = [](int n) { return dim3((n + 255) / 256); };
    transpose_bf16_kernel<<<tgrid(DIM * 2 * DI), 256, 0, stream>>>(gru1_w, w1T, DIM, 2 * DI, DIM, 0);
    transpose_bf16_kernel<<<tgrid(DIM * 2 * DI), 256, 0, stream>>>(gru2_w, w2T, DIM, 2 * DI, DIM, 0);
    transpose_bf16_kernel<<<tgrid(DI * DIM), 256, 0, stream>>>(gru1_o, ocT, DI, DIM, 2 * DI, 0);
    transpose_bf16_kernel<<<tgrid(DI * DIM), 256, 0, stream>>>(gru2_o, ocT, DI, DIM, 2 * DI, DI);
    transpose_bf16_kernel<<<tgrid(DIM * MLP_DIM), 256, 0, stream>>>(p1_w, p1T, DIM, MLP_DIM, DIM, 0);
    transpose_bf16_kernel<<<tgrid(MLP_DIM * DIM), 256, 0, stream>>>(p2_w, p2T, MLP_DIM, DIM, MLP_DIM, 0);

    ln_kernel<__hip_bfloat16><<<dim3(M / 4), 256, 0, stream>>>(x, gamma1, beta1, xnb);
    dwconv_kernel<<<dim3((M * DIM) / 256), 256, 0, stream>>>(xnb, dwc_w, dwc_b, xs);

    const int scan_blocks = NB * CHUNKS * DI / 256;  // 3072
    // GRU1: hg = xs @ w1; scan fwd -> h1 (hbuf, stride DI)
    gemm_bt<<<dim3(2 * DI / 128, M / 128), 256, 0, stream>>>(xs, DIM, xs, DIM, DIM, w1T, M, 2 * DI, DIM,
                                                             hg, nullptr, nullptr, nullptr, 0);
    scan_part1<<<dim3(scan_blocks), 256, 0, stream>>>(hg, summ, 0);
    scan_part2<<<dim3(scan_blocks), 256, 0, stream>>>(hg, summ, hbuf, 0, DI);
    // GRU2: hg = xs @ w2; scan bwd -> h2 in-place into hg[:, 0:DI] (stride 2*DI)
    gemm_bt<<<dim3(2 * DI / 128, M / 128), 256, 0, stream>>>(xs, DIM, xs, DIM, DIM, w2T, M, 2 * DI, DIM,
                                                             hg, nullptr, nullptr, nullptr, 0);
    scan_part1<<<dim3(scan_blocks), 256, 0, stream>>>(hg, summ, 1);
    scan_part2<<<dim3(scan_blocks), 256, 0, stream>>>(hg, summ, hg, 1, 2 * DI);

    // merged GRU out: y = [h1 | h2] @ [o1;o2] + x   (K=1536)
    gemm_bt<<<dim3(DIM / 128, M / 128), 256, 0, stream>>>(hbuf, DI, hg, 2 * DI, DI, ocT, M, DIM, 2 * DI,
                                                          nullptr, y, nullptr, x, 0);

    // LN2 + MLP
    ln_kernel<__hip_bfloat16><<<dim3(M / 4), 256, 0, stream>>>(y, gamma2, beta2, yn);
    gemm_bt<<<dim3(MLP_DIM / 128, M / 128), 256, 0, stream>>>(yn, DIM, yn, DIM, DIM, p1T, M, MLP_DIM, DIM,
                                                              t1, nullptr, p1_b, nullptr, 1);
    gemm_bt<<<dim3(DIM / 128, M / 128), 256, 0, stream>>>(t1, MLP_DIM, t1, MLP_DIM, MLP_DIM, p2T, M, DIM, MLP_DIM,
                                                          nullptr, out, p2_b, y, 0);
}

// Round 2
// 719.585 us; speedup vs baseline: 1.1702x; 1.0656x over previous
//
#include <hip/hip_runtime.h>
#include <hip/hip_bf16.h>

#define DIM 384
#define DI 768
#define S_LEN 1024
#define NB 32
#define M_ROWS (NB * S_LEN)   // 32768
#define MLP_DIM 1536
#define CHUNKS 32
#define CLEN (S_LEN / CHUNKS)  // 32

typedef __bf16 bf16x8 __attribute__((ext_vector_type(8)));
typedef float f32x4 __attribute__((ext_vector_type(4)));

#define GLOBAL_AS __attribute__((address_space(1)))
#define LDS_AS __attribute__((address_space(3)))

// ---------------- LayerNorm: one wave per row of 384 ----------------
template <typename OutT>
__global__ __launch_bounds__(256) void ln_kernel(const float* __restrict__ x,
                                                 const float* __restrict__ gamma,
                                                 const float* __restrict__ beta,
                                                 OutT* __restrict__ out) {
    int row = blockIdx.x * 4 + (threadIdx.x >> 6);
    int lane = threadIdx.x & 63;
    const float* xr = x + (size_t)row * DIM;
    float v[6];
    float s = 0.f, sq = 0.f;
#pragma unroll
    for (int i = 0; i < 6; ++i) {
        v[i] = xr[lane + i * 64];
        s += v[i];
        sq += v[i] * v[i];
    }
#pragma unroll
    for (int off = 32; off > 0; off >>= 1) {
        s += __shfl_down(s, off);
        sq += __shfl_down(sq, off);
    }
    s = __shfl(s, 0);
    sq = __shfl(sq, 0);
    float mean = s * (1.f / DIM);
    float var = sq * (1.f / DIM) - mean * mean;
    float rstd = rsqrtf(var + 1e-5f);
    OutT* orow = out + (size_t)row * DIM;
#pragma unroll
    for (int i = 0; i < 6; ++i) {
        int c = lane + i * 64;
        float y = (v[i] - mean) * rstd * gamma[c] + beta[c];
        if constexpr (sizeof(OutT) == 2)
            orow[c] = __float2bfloat16(y);
        else
            orow[c] = y;
    }
}

// ------- Depthwise 3x3 conv, vectorized: each thread does 8 consecutive channels -------
// xn channel-last [n][s][c] bf16; taps are bf16x8 16B loads; weights (c*9 contiguous
// floats) hoisted to registers via float4 loads (L1-resident, 13.8 KB total).
__global__ __launch_bounds__(256) void dwconv_kernel(const __hip_bfloat16* __restrict__ xn,
                                                     const float* __restrict__ w,
                                                     const float* __restrict__ b,
                                                     __hip_bfloat16* __restrict__ xs) {
    const int CB = DIM / 8;  // 48 channel-blocks per position
    size_t tid = (size_t)blockIdx.x * 256 + threadIdx.x;
    int cb = (int)(tid % CB);
    int s = (int)((tid / CB) % S_LEN);
    int n = (int)(tid / ((size_t)CB * S_LEN));
    int c = cb * 8;
    int h0 = s >> 5, w0 = s & 31;

    // weights: w[c*9 .. c*9+71] contiguous, 16B-aligned (c%8==0 -> c*36 bytes % 16 == 0)
    float wv[72];
    {
        const float4* wp = (const float4*)(w + (size_t)c * 9);
#pragma unroll
        for (int i = 0; i < 18; ++i) ((float4*)wv)[i] = wp[i];
    }
    float acc[8];
    {
        const float4 b0 = *(const float4*)&b[c];
        const float4 b1 = *(const float4*)&b[c + 4];
        acc[0] = b0.x; acc[1] = b0.y; acc[2] = b0.z; acc[3] = b0.w;
        acc[4] = b1.x; acc[5] = b1.y; acc[6] = b1.z; acc[7] = b1.w;
    }

    const __hip_bfloat16* base = xn + (size_t)n * S_LEN * DIM + c;
#pragma unroll
    for (int kh = 0; kh < 3; ++kh) {
        int hh = h0 + kh - 1;
        if (hh < 0 || hh > 31) continue;
#pragma unroll
        for (int kw = 0; kw < 3; ++kw) {
            int ww = w0 + kw - 1;
            if (ww < 0 || ww > 31) continue;
            bf16x8 xv = *(const bf16x8*)&base[(size_t)(hh * 32 + ww) * DIM];
#pragma unroll
            for (int e = 0; e < 8; ++e)
                acc[e] += (float)xv[e] * wv[e * 9 + kh * 3 + kw];
        }
    }
    bf16x8 ov;
#pragma unroll
    for (int e = 0; e < 8; ++e) ov[e] = (__bf16)acc[e];
    *(bf16x8*)&xs[tid * 8] = ov;
}

// ------- transpose + cast f32 -> bf16: out[c*ostride + ooff + r] = in[r*C + c] -------
__global__ __launch_bounds__(256) void transpose_bf16_kernel(const float* __restrict__ in,
                                                             __hip_bfloat16* __restrict__ out,
                                                             int R, int C, int ostride, int ooff) {
    int idx = blockIdx.x * 256 + threadIdx.x;
    if (idx >= R * C) return;
    int r = idx / C, c = idx % C;
    out[(size_t)c * ostride + ooff + r] = __float2bfloat16(in[idx]);
}

// ---------------- minGRU chunked scan ----------------
__device__ __forceinline__ void gru_ab(float hid, float gate, float& a, float& bv) {
    float z = 1.f / (1.f + __expf(-gate));
    float gh = (hid >= 0.f) ? (hid + 0.5f) : (1.f / (1.f + __expf(-hid)));
    a = 1.f - z;
    bv = z * gh;
}

__global__ __launch_bounds__(256) void scan_part1(const __hip_bfloat16* __restrict__ hg,
                                                  float* __restrict__ summ, int rev) {
    int tid = blockIdx.x * 256 + threadIdx.x;  // NB*CHUNKS*DI
    int c = tid % DI;
    int j = (tid / DI) % CHUNKS;
    int b = tid / (DI * CHUNKS);
    const __hip_bfloat16* base = hg + (size_t)b * S_LEN * (2 * DI);
    float A = 1.f, Bv = 0.f;
    for (int i = 0; i < CLEN; i += 8) {
        float hid[8], gate[8];
#pragma unroll
        for (int q = 0; q < 8; ++q) {
            int pos = j * CLEN + i + q;
            int t = rev ? (S_LEN - 1 - pos) : pos;
            hid[q] = __bfloat162float(base[(size_t)t * (2 * DI) + c]);
            gate[q] = __bfloat162float(base[(size_t)t * (2 * DI) + DI + c]);
        }
#pragma unroll
        for (int q = 0; q < 8; ++q) {
            float a, bv;
            gru_ab(hid[q], gate[q], a, bv);
            A *= a;
            Bv = a * Bv + bv;
        }
    }
    int idx = (j * NB + b) * DI + c;
    summ[idx] = A;
    summ[(size_t)CHUNKS * NB * DI + idx] = Bv;
}

// part2: writes h with row stride `ostride`; may alias hg in-place (1:1 read-before-write)
__global__ __launch_bounds__(256) void scan_part2(const __hip_bfloat16* __restrict__ hg,
                                                  const float* __restrict__ summ,
                                                  __hip_bfloat16* __restrict__ ho, int rev,
                                                  int ostride) {
    int tid = blockIdx.x * 256 + threadIdx.x;
    int c = tid % DI;
    int j = (tid / DI) % CHUNKS;
    int b = tid / (DI * CHUNKS);
    const float* sB = summ + (size_t)CHUNKS * NB * DI;
    float h = 0.f;
    for (int jp = 0; jp < j; ++jp) {
        int idx = (jp * NB + b) * DI + c;
        h = summ[idx] * h + sB[idx];
    }
    const __hip_bfloat16* base = hg + (size_t)b * S_LEN * (2 * DI);
    __hip_bfloat16* hob = ho + (size_t)b * S_LEN * ostride;
    for (int i = 0; i < CLEN; i += 8) {
        float hid[8], gate[8];
        int tt[8];
#pragma unroll
        for (int q = 0; q < 8; ++q) {
            int pos = j * CLEN + i + q;
            int t = rev ? (S_LEN - 1 - pos) : pos;
            tt[q] = t;
            hid[q] = __bfloat162float(base[(size_t)t * (2 * DI) + c]);
            gate[q] = __bfloat162float(base[(size_t)t * (2 * DI) + DI + c]);
        }
#pragma unroll
        for (int q = 0; q < 8; ++q) {
            float a, bv;
            gru_ab(hid[q], gate[q], a, bv);
            h = a * h + bv;
            hob[(size_t)tt[q] * ostride + c] = __float2bfloat16(h);
        }
    }
}

// ------- bf16 MFMA GEMM: dual-A (k-split), global_load_lds staging, depth-2 prefetch -------
// out = [A1|A2](MxK) @ B(KxN); Bt is N x K. MFMA as (b,a): lane -> row m (lr), 4 consecutive cols.
// Pipeline: 3 LDS buffers, stage(t+2) at top of iter t, counted s_waitcnt vmcnt(8) before the
// producer barrier (loads for t+1/t+2 stay in flight across it). lgkmcnt(0)+barrier after the
// MFMAs fences the WAR: stage(t+2) overwrites buf[(t-1)%3], last read in iter t-1.
// XCD-chunked tile swizzle: blocks sharing an A-panel land on one XCD's L2 (all grids %8==0).
__global__ __launch_bounds__(256) void gemm_bt(const __hip_bfloat16* __restrict__ A1, int lda1,
                                               const __hip_bfloat16* __restrict__ A2, int lda2,
                                               int ksplit,
                                               const __hip_bfloat16* __restrict__ Bt,
                                               int M, int N, int K,
                                               __hip_bfloat16* __restrict__ outH,
                                               float* __restrict__ outF,
                                               const float* __restrict__ bias,
                                               const float* __restrict__ add,
                                               int act) {
    __shared__ __align__(16) __hip_bfloat16 sA[3][128 * 32];
    __shared__ __align__(16) __hip_bfloat16 sB[3][128 * 32];
    int t = threadIdx.x;

    // XCD swizzle: hardware round-robins consecutive block ids across 8 XCDs; remap so each
    // XCD processes a contiguous chunk of tiles (contiguous M-panels -> A panel fits its L2).
    int nwg = gridDim.x * gridDim.y;
    int bid = blockIdx.y * gridDim.x + blockIdx.x;
    int cpx = nwg >> 3;  // all gemm grids here are divisible by 8 (bijective)
    int tile = (bid & 7) * cpx + (bid >> 3);
    int bx = tile % gridDim.x;
    int by = tile / gridDim.x;
    int n0 = bx * 128;
    int m0 = by * 128;

    int wave = t >> 6, lane = t & 63;
    int wm = (wave >> 1) << 6, wn = (wave & 1) << 6;
    int quad = lane >> 4, lr = lane & 15;

    f32x4 acc[4][4];
#pragma unroll
    for (int i = 0; i < 4; ++i)
#pragma unroll
        for (int j = 0; j < 4; ++j)
#pragma unroll
            for (int e = 0; e < 4; ++e) acc[i][j][e] = 0.f;

    int ch0 = wave * 128 + lane;
    int ch1 = wave * 128 + 64 + lane;
    int r0 = ch0 >> 2, g0 = (ch0 & 3) * 8;
    int r1 = ch1 >> 2, g1 = (ch1 & 3) * 8;

    const int KT = K >> 5;  // #32-wide k-tiles (>= 12 for all calls)

    auto stage = [&](int kt) {
        int k0 = kt << 5;
        const __hip_bfloat16* Ab;
        int ldx, kk;
        if (k0 < ksplit) { Ab = A1; ldx = lda1; kk = k0; }
        else             { Ab = A2; ldx = lda2; kk = k0 - ksplit; }
        int bi = kt % 3;
        __builtin_amdgcn_global_load_lds((const GLOBAL_AS void*)(Ab + (size_t)(m0 + r0) * ldx + kk + g0),
                                         (LDS_AS void*)&sA[bi][ch0 * 8], 16, 0, 0);
        __builtin_amdgcn_global_load_lds((const GLOBAL_AS void*)(Ab + (size_t)(m0 + r1) * ldx + kk + g1),
                                         (LDS_AS void*)&sA[bi][ch1 * 8], 16, 0, 0);
        __builtin_amdgcn_global_load_lds((const GLOBAL_AS void*)(Bt + (size_t)(n0 + r0) * K + k0 + g0),
                                         (LDS_AS void*)&sB[bi][ch0 * 8], 16, 0, 0);
        __builtin_amdgcn_global_load_lds((const GLOBAL_AS void*)(Bt + (size_t)(n0 + r1) * K + k0 + g1),
                                         (LDS_AS void*)&sB[bi][ch1 * 8], 16, 0, 0);
    };

    stage(0);
    stage(1);
    for (int kt = 0; kt < KT; ++kt) {
        if (kt + 2 < KT) {
            stage(kt + 2);
            // 12 loads may be outstanding; keep the 8 newest (tiles kt+1, kt+2) in flight.
            asm volatile("s_waitcnt vmcnt(8)" ::: "memory");
        } else if (kt + 2 == KT) {
            asm volatile("s_waitcnt vmcnt(4)" ::: "memory");
        } else {
            asm volatile("s_waitcnt vmcnt(0)" ::: "memory");
        }
        __builtin_amdgcn_s_barrier();  // buf[kt%3] ready for all waves
        int bi = kt % 3;
        bf16x8 af[4], bfr[4];
#pragma unroll
        for (int mi = 0; mi < 4; ++mi)
            af[mi] = *(const bf16x8*)&sA[bi][(wm + mi * 16 + lr) * 32 + quad * 8];
#pragma unroll
        for (int ni = 0; ni < 4; ++ni)
            bfr[ni] = *(const bf16x8*)&sB[bi][(wn + ni * 16 + lr) * 32 + quad * 8];
#pragma unroll
        for (int mi = 0; mi < 4; ++mi)
#pragma unroll
            for (int ni = 0; ni < 4; ++ni)
                acc[mi][ni] = __builtin_amdgcn_mfma_f32_16x16x32_bf16(bfr[ni], af[mi], acc[mi][ni], 0, 0, 0);
        // All ds_reads of buf[kt%3] must land before any wave's stage(kt+3) overwrites it.
        asm volatile("s_waitcnt lgkmcnt(0)" ::: "memory");
        __builtin_amdgcn_s_barrier();
    }

    // epilogue: row = m0+wm+mi*16+lr, cols = n0+wn+ni*16+quad*4 .. +3 (plain stores; L2 merges)
#pragma unroll
    for (int mi = 0; mi < 4; ++mi) {
        int row = m0 + wm + mi * 16 + lr;
#pragma unroll
        for (int ni = 0; ni < 4; ++ni) {
            int col = n0 + wn + ni * 16 + quad * 4;
            size_t idx = (size_t)row * N + col;
            f32x4 v = acc[mi][ni];
            if (bias) {
                const float4 b4 = *(const float4*)&bias[col];
                v[0] += b4.x; v[1] += b4.y; v[2] += b4.z; v[3] += b4.w;
            }
            if (act == 1) {
#pragma unroll
                for (int e = 0; e < 4; ++e) {
                    // tanh-approx gelu (max dev ~3e-4 vs exact; vanishes through next GEMM)
                    float xv = v[e];
                    float u = 0.7978845608f * (xv + 0.044715f * xv * xv * xv);
                    float ex = __expf(2.f * u);
                    float th = (ex - 1.f) / (ex + 1.f);
                    v[e] = 0.5f * xv * (1.f + th);
                }
            }
            if (add) {
                const float4 a4 = *(const float4*)&add[idx];
                v[0] += a4.x; v[1] += a4.y; v[2] += a4.z; v[3] += a4.w;
            }
            if (outH) {
                union { __hip_bfloat16 h[4]; int2 i2; } u;
                u.h[0] = __float2bfloat16(v[0]);
                u.h[1] = __float2bfloat16(v[1]);
                u.h[2] = __float2bfloat16(v[2]);
                u.h[3] = __float2bfloat16(v[3]);
                *(int2*)&outH[idx] = u.i2;
            } else {
                *(float4*)&outF[idx] = make_float4(v[0], v[1], v[2], v[3]);
            }
        }
    }
}

extern "C" void kernel_launch(void* const* d_in, const int* in_sizes, int n_in,
                              void* d_out, int out_size, void* d_ws, size_t ws_size,
                              hipStream_t stream) {
    const float* x = (const float*)d_in[0];
    const float* gamma1 = (const float*)d_in[1];
    const float* beta1 = (const float*)d_in[2];
    const float* dwc_w = (const float*)d_in[3];
    const float* dwc_b = (const float*)d_in[4];
    const float* gru1_w = (const float*)d_in[5];
    const float* gru1_o = (const float*)d_in[6];
    const float* gru2_w = (const float*)d_in[7];
    const float* gru2_o = (const float*)d_in[8];
    const float* gamma2 = (const float*)d_in[9];
    const float* beta2 = (const float*)d_in[10];
    const float* p1_w = (const float*)d_in[11];
    const float* p1_b = (const float*)d_in[12];
    const float* p2_w = (const float*)d_in[13];
    const float* p2_b = (const float*)d_in[14];
    float* out = (float*)d_out;

    char* ws = (char*)d_ws;
    size_t off = 0;
    auto alloc = [&](size_t b) {
        char* p = ws + off;
        off += (b + 255) & ~(size_t)255;
        return p;
    };
    const size_t M = M_ROWS;
    // ws total ~188 MB
    __hip_bfloat16* hg = (__hip_bfloat16*)alloc(M * 2 * DI * 2);    // 100.7 MB; h2 in-place; later t1
    __hip_bfloat16* hbuf = (__hip_bfloat16*)alloc(M * DI * 2);      // 50.3 MB: LN1-bf16 out, then h1
    __hip_bfloat16* xs = (__hip_bfloat16*)alloc(M * DIM * 2);       // 25.2 MB; later yn
    float* summ = (float*)alloc((size_t)2 * CHUNKS * NB * DI * 4);  // 6.3 MB
    __hip_bfloat16* w1T = (__hip_bfloat16*)alloc((size_t)DIM * 2 * DI * 2);
    __hip_bfloat16* w2T = (__hip_bfloat16*)alloc((size_t)DIM * 2 * DI * 2);
    __hip_bfloat16* ocT = (__hip_bfloat16*)alloc((size_t)DIM * 2 * DI * 2);  // 384 x 1536 = [o1;o2]^T
    __hip_bfloat16* p1T = (__hip_bfloat16*)alloc((size_t)DIM * MLP_DIM * 2);
    __hip_bfloat16* p2T = (__hip_bfloat16*)alloc((size_t)MLP_DIM * DIM * 2);
    __hip_bfloat16* xnb = hbuf;           // LN1 out (bf16); dead after dwconv, before scan1
    float* y = (float*)d_out;             // post-GRU residual; same-idx RMW only
    __hip_bfloat16* yn = xs;              // LN2 out; xs dead after GRU2 input GEMM
    __hip_bfloat16* t1 = hg;              // MLP hidden; hg dead after scan2

    auto tgrid = [](int n) { return dim3((n + 255) / 256); };
    transpose_bf16_kernel<<<tgrid(DIM * 2 * DI), 256, 0, stream>>>(gru1_w, w1T, DIM, 2 * DI, DIM, 0);
    transpose_bf16_kernel<<<tgrid(DIM * 2 * DI), 256, 0, stream>>>(gru2_w, w2T, DIM, 2 * DI, DIM, 0);
    transpose_bf16_kernel<<<tgrid(DI * DIM), 256, 0, stream>>>(gru1_o, ocT, DI, DIM, 2 * DI, 0);
    transpose_bf16_kernel<<<tgrid(DI * DIM), 256, 0, stream>>>(gru2_o, ocT, DI, DIM, 2 * DI, DI);
    transpose_bf16_kernel<<<tgrid(DIM * MLP_DIM), 256, 0, stream>>>(p1_w, p1T, DIM, MLP_DIM, DIM, 0);
    transpose_bf16_kernel<<<tgrid(MLP_DIM * DIM), 256, 0, stream>>>(p2_w, p2T, MLP_DIM, DIM, MLP_DIM, 0);

    ln_kernel<__hip_bfloat16><<<dim3(M / 4), 256, 0, stream>>>(x, gamma1, beta1, xnb);
    dwconv_kernel<<<dim3((int)((M * DIM / 8) / 256)), 256, 0, stream>>>(xnb, dwc_w, dwc_b, xs);

    const int scan_blocks = NB * CHUNKS * DI / 256;  // 3072
    // GRU1: hg = xs @ w1; scan fwd -> h1 (hbuf, stride DI)
    gemm_bt<<<dim3(2 * DI / 128, M / 128), 256, 0, stream>>>(xs, DIM, xs, DIM, DIM, w1T, M, 2 * DI, DIM,
                                                             hg, nullptr, nullptr, nullptr, 0);
    scan_part1<<<dim3(scan_blocks), 256, 0, stream>>>(hg, summ, 0);
    scan_part2<<<dim3(scan_blocks), 256, 0, stream>>>(hg, summ, hbuf, 0, DI);
    // GRU2: hg = xs @ w2; scan bwd -> h2 in-place into hg[:, 0:DI] (stride 2*DI)
    gemm_bt<<<dim3(2 * DI / 128, M / 128), 256, 0, stream>>>(xs, DIM, xs, DIM, DIM, w2T, M, 2 * DI, DIM,
                                                             hg, nullptr, nullptr, nullptr, 0);
    scan_part1<<<dim3(scan_blocks), 256, 0, stream>>>(hg, summ, 1);
    scan_part2<<<dim3(scan_blocks), 256, 0, stream>>>(hg, summ, hg, 1, 2 * DI);

    // merged GRU out: y = [h1 | h2] @ [o1;o2] + x   (K=1536)
    gemm_bt<<<dim3(DIM / 128, M / 128), 256, 0, stream>>>(hbuf, DI, hg, 2 * DI, DI, ocT, M, DIM, 2 * DI,
                                                          nullptr, y, nullptr, x, 0);

    // LN2 + MLP
    ln_kernel<__hip_bfloat16><<<dim3(M / 4), 256, 0, stream>>>(y, gamma2, beta2, yn);
    gemm_bt<<<dim3(MLP_DIM / 128, M / 128), 256, 0, stream>>>(yn, DIM, yn, DIM, DIM, p1T, M, MLP_DIM, DIM,
                                                              t1, nullptr, p1_b, nullptr, 1);
    gemm_bt<<<dim3(DIM / 128, M / 128), 256, 0, stream>>>(t1, MLP_DIM, t1, MLP_DIM, MLP_DIM, p2T, M, DIM, MLP_DIM,
                                                          nullptr, out, p2_b, y, 0);
}

// Round 3
// 714.445 us; speedup vs baseline: 1.1786x; 1.0072x over previous
//
#include <hip/hip_runtime.h>
#include <hip/hip_bf16.h>

#define DIM 384
#define DI 768
#define S_LEN 1024
#define NB 32
#define M_ROWS (NB * S_LEN)   // 32768
#define MLP_DIM 1536
#define CHUNKS 32
#define CLEN (S_LEN / CHUNKS)  // 32

typedef __bf16 bf16x8 __attribute__((ext_vector_type(8)));
typedef float f32x4 __attribute__((ext_vector_type(4)));

#define GLOBAL_AS __attribute__((address_space(1)))
#define LDS_AS __attribute__((address_space(3)))

// ---------------- LayerNorm: one wave per row of 384 ----------------
template <typename OutT>
__global__ __launch_bounds__(256) void ln_kernel(const float* __restrict__ x,
                                                 const float* __restrict__ gamma,
                                                 const float* __restrict__ beta,
                                                 OutT* __restrict__ out) {
    int row = blockIdx.x * 4 + (threadIdx.x >> 6);
    int lane = threadIdx.x & 63;
    const float* xr = x + (size_t)row * DIM;
    float v[6];
    float s = 0.f, sq = 0.f;
#pragma unroll
    for (int i = 0; i < 6; ++i) {
        v[i] = xr[lane + i * 64];
        s += v[i];
        sq += v[i] * v[i];
    }
#pragma unroll
    for (int off = 32; off > 0; off >>= 1) {
        s += __shfl_down(s, off);
        sq += __shfl_down(sq, off);
    }
    s = __shfl(s, 0);
    sq = __shfl(sq, 0);
    float mean = s * (1.f / DIM);
    float var = sq * (1.f / DIM) - mean * mean;
    float rstd = rsqrtf(var + 1e-5f);
    OutT* orow = out + (size_t)row * DIM;
#pragma unroll
    for (int i = 0; i < 6; ++i) {
        int c = lane + i * 64;
        float y = (v[i] - mean) * rstd * gamma[c] + beta[c];
        if constexpr (sizeof(OutT) == 2)
            orow[c] = __float2bfloat16(y);
        else
            orow[c] = y;
    }
}

// ------- Depthwise 3x3 conv, vectorized: each thread does 8 consecutive channels -------
// xn channel-last [n][s][c] bf16; taps are bf16x8 16B loads; weights (c*9 contiguous
// floats) hoisted to registers via float4 loads (L1-resident, 13.8 KB total).
__global__ __launch_bounds__(256) void dwconv_kernel(const __hip_bfloat16* __restrict__ xn,
                                                     const float* __restrict__ w,
                                                     const float* __restrict__ b,
                                                     __hip_bfloat16* __restrict__ xs) {
    const int CB = DIM / 8;  // 48 channel-blocks per position
    size_t tid = (size_t)blockIdx.x * 256 + threadIdx.x;
    int cb = (int)(tid % CB);
    int s = (int)((tid / CB) % S_LEN);
    int n = (int)(tid / ((size_t)CB * S_LEN));
    int c = cb * 8;
    int h0 = s >> 5, w0 = s & 31;

    // weights: w[c*9 .. c*9+71] contiguous, 16B-aligned (c%8==0 -> c*36 bytes % 16 == 0)
    float wv[72];
    {
        const float4* wp = (const float4*)(w + (size_t)c * 9);
#pragma unroll
        for (int i = 0; i < 18; ++i) ((float4*)wv)[i] = wp[i];
    }
    float acc[8];
    {
        const float4 b0 = *(const float4*)&b[c];
        const float4 b1 = *(const float4*)&b[c + 4];
        acc[0] = b0.x; acc[1] = b0.y; acc[2] = b0.z; acc[3] = b0.w;
        acc[4] = b1.x; acc[5] = b1.y; acc[6] = b1.z; acc[7] = b1.w;
    }

    const __hip_bfloat16* base = xn + (size_t)n * S_LEN * DIM + c;
#pragma unroll
    for (int kh = 0; kh < 3; ++kh) {
        int hh = h0 + kh - 1;
        if (hh < 0 || hh > 31) continue;
#pragma unroll
        for (int kw = 0; kw < 3; ++kw) {
            int ww = w0 + kw - 1;
            if (ww < 0 || ww > 31) continue;
            bf16x8 xv = *(const bf16x8*)&base[(size_t)(hh * 32 + ww) * DIM];
#pragma unroll
            for (int e = 0; e < 8; ++e)
                acc[e] += (float)xv[e] * wv[e * 9 + kh * 3 + kw];
        }
    }
    bf16x8 ov;
#pragma unroll
    for (int e = 0; e < 8; ++e) ov[e] = (__bf16)acc[e];
    *(bf16x8*)&xs[tid * 8] = ov;
}

// ------- transpose + cast f32 -> bf16: out[c*ostride + ooff + r] = in[r*C + c] -------
__global__ __launch_bounds__(256) void transpose_bf16_kernel(const float* __restrict__ in,
                                                             __hip_bfloat16* __restrict__ out,
                                                             int R, int C, int ostride, int ooff) {
    int idx = blockIdx.x * 256 + threadIdx.x;
    if (idx >= R * C) return;
    int r = idx / C, c = idx % C;
    out[(size_t)c * ostride + ooff + r] = __float2bfloat16(in[idx]);
}

// ---------------- minGRU chunked scan ----------------
__device__ __forceinline__ void gru_ab(float hid, float gate, float& a, float& bv) {
    float z = 1.f / (1.f + __expf(-gate));
    float gh = (hid >= 0.f) ? (hid + 0.5f) : (1.f / (1.f + __expf(-hid)));
    a = 1.f - z;
    bv = z * gh;
}

__global__ __launch_bounds__(256) void scan_part1(const __hip_bfloat16* __restrict__ hg,
                                                  float* __restrict__ summ, int rev) {
    int tid = blockIdx.x * 256 + threadIdx.x;  // NB*CHUNKS*DI
    int c = tid % DI;
    int j = (tid / DI) % CHUNKS;
    int b = tid / (DI * CHUNKS);
    const __hip_bfloat16* base = hg + (size_t)b * S_LEN * (2 * DI);
    float A = 1.f, Bv = 0.f;
    for (int i = 0; i < CLEN; i += 8) {
        float hid[8], gate[8];
#pragma unroll
        for (int q = 0; q < 8; ++q) {
            int pos = j * CLEN + i + q;
            int t = rev ? (S_LEN - 1 - pos) : pos;
            hid[q] = __bfloat162float(base[(size_t)t * (2 * DI) + c]);
            gate[q] = __bfloat162float(base[(size_t)t * (2 * DI) + DI + c]);
        }
#pragma unroll
        for (int q = 0; q < 8; ++q) {
            float a, bv;
            gru_ab(hid[q], gate[q], a, bv);
            A *= a;
            Bv = a * Bv + bv;
        }
    }
    int idx = (j * NB + b) * DI + c;
    summ[idx] = A;
    summ[(size_t)CHUNKS * NB * DI + idx] = Bv;
}

// part2: writes h with row stride `ostride`; may alias hg in-place (1:1 read-before-write)
__global__ __launch_bounds__(256) void scan_part2(const __hip_bfloat16* __restrict__ hg,
                                                  const float* __restrict__ summ,
                                                  __hip_bfloat16* __restrict__ ho, int rev,
                                                  int ostride) {
    int tid = blockIdx.x * 256 + threadIdx.x;
    int c = tid % DI;
    int j = (tid / DI) % CHUNKS;
    int b = tid / (DI * CHUNKS);
    const float* sB = summ + (size_t)CHUNKS * NB * DI;
    float h = 0.f;
    for (int jp = 0; jp < j; ++jp) {
        int idx = (jp * NB + b) * DI + c;
        h = summ[idx] * h + sB[idx];
    }
    const __hip_bfloat16* base = hg + (size_t)b * S_LEN * (2 * DI);
    __hip_bfloat16* hob = ho + (size_t)b * S_LEN * ostride;
    for (int i = 0; i < CLEN; i += 8) {
        float hid[8], gate[8];
        int tt[8];
#pragma unroll
        for (int q = 0; q < 8; ++q) {
            int pos = j * CLEN + i + q;
            int t = rev ? (S_LEN - 1 - pos) : pos;
            tt[q] = t;
            hid[q] = __bfloat162float(base[(size_t)t * (2 * DI) + c]);
            gate[q] = __bfloat162float(base[(size_t)t * (2 * DI) + DI + c]);
        }
#pragma unroll
        for (int q = 0; q < 8; ++q) {
            float a, bv;
            gru_ab(hid[q], gate[q], a, bv);
            h = a * h + bv;
            hob[(size_t)tt[q] * ostride + c] = __float2bfloat16(h);
        }
    }
}

// ------- bf16 MFMA GEMM: dual-A (k-split), global_load_lds staging, depth-2 prefetch -------
// out = [A1|A2](MxK) @ B(KxN); Bt is N x K. MFMA as (b,a): lane -> row m (lr), 4 consecutive cols.
// Pipeline: 3 LDS buffers, stage(t+2) at top of iter t, counted s_waitcnt vmcnt(8) before the
// producer barrier (loads for t+1/t+2 stay in flight across it). lgkmcnt(0)+barrier after the
// MFMAs fences the WAR: stage(t+2) overwrites buf[(t-1)%3], last read in iter t-1.
// XCD-chunked tile swizzle: blocks sharing an A-panel land on one XCD's L2 (all grids %8==0).
// T2 LDS swizzle (G21 both-sides): rows are 64B (4x 16B slots); unswizzled, a 16-lane ds_read
// group is 8-way bank-conflicted (even rows all hit one 4-bank group). We store
// LDS[row][s] = global[row][s ^ f(row)], f(row)=(row>>1)&3, by permuting the *global source*
// slot in stage (global_load_lds dest stays linear), and read with quad ^ f(row). 16
// consecutive rows then cover all 8 bank groups at 2 lanes each (2-way = free, m136).
// f reduces to (lr>>1)&3 on the read side (wm/wn, mi*16 are 0 mod 8) -> loop-invariant.
__global__ __launch_bounds__(256) void gemm_bt(const __hip_bfloat16* __restrict__ A1, int lda1,
                                               const __hip_bfloat16* __restrict__ A2, int lda2,
                                               int ksplit,
                                               const __hip_bfloat16* __restrict__ Bt,
                                               int M, int N, int K,
                                               __hip_bfloat16* __restrict__ outH,
                                               float* __restrict__ outF,
                                               const float* __restrict__ bias,
                                               const float* __restrict__ add,
                                               int act) {
    __shared__ __align__(16) __hip_bfloat16 sA[3][128 * 32];
    __shared__ __align__(16) __hip_bfloat16 sB[3][128 * 32];
    int t = threadIdx.x;

    // XCD swizzle: hardware round-robins consecutive block ids across 8 XCDs; remap so each
    // XCD processes a contiguous chunk of tiles (contiguous M-panels -> A panel fits its L2).
    int nwg = gridDim.x * gridDim.y;
    int bid = blockIdx.y * gridDim.x + blockIdx.x;
    int cpx = nwg >> 3;  // all gemm grids here are divisible by 8 (bijective)
    int tile = (bid & 7) * cpx + (bid >> 3);
    int bx = tile % gridDim.x;
    int by = tile / gridDim.x;
    int n0 = bx * 128;
    int m0 = by * 128;

    int wave = t >> 6, lane = t & 63;
    int wm = (wave >> 1) << 6, wn = (wave & 1) << 6;
    int quad = lane >> 4, lr = lane & 15;

    f32x4 acc[4][4];
#pragma unroll
    for (int i = 0; i < 4; ++i)
#pragma unroll
        for (int j = 0; j < 4; ++j)
#pragma unroll
            for (int e = 0; e < 4; ++e) acc[i][j][e] = 0.f;

    int ch0 = wave * 128 + lane;
    int ch1 = wave * 128 + 64 + lane;
    // stage-side swizzle: thread covering LDS (row r, slot s=ch&3) fetches global slot s^f(r)
    int r0 = ch0 >> 2, g0 = (((ch0 & 3) ^ ((r0 >> 1) & 3)) * 8);
    int r1 = ch1 >> 2, g1 = (((ch1 & 3) ^ ((r1 >> 1) & 3)) * 8);
    // read-side swizzle offset (loop-invariant): element offset (quad ^ (lr>>1)&3)*8
    int qx = (quad ^ ((lr >> 1) & 3)) * 8;

    const int KT = K >> 5;  // #32-wide k-tiles (>= 12 for all calls)

    auto stage = [&](int kt) {
        int k0 = kt << 5;
        const __hip_bfloat16* Ab;
        int ldx, kk;
        if (k0 < ksplit) { Ab = A1; ldx = lda1; kk = k0; }
        else             { Ab = A2; ldx = lda2; kk = k0 - ksplit; }
        int bi = kt % 3;
        __builtin_amdgcn_global_load_lds((const GLOBAL_AS void*)(Ab + (size_t)(m0 + r0) * ldx + kk + g0),
                                         (LDS_AS void*)&sA[bi][ch0 * 8], 16, 0, 0);
        __builtin_amdgcn_global_load_lds((const GLOBAL_AS void*)(Ab + (size_t)(m0 + r1) * ldx + kk + g1),
                                         (LDS_AS void*)&sA[bi][ch1 * 8], 16, 0, 0);
        __builtin_amdgcn_global_load_lds((const GLOBAL_AS void*)(Bt + (size_t)(n0 + r0) * K + k0 + g0),
                                         (LDS_AS void*)&sB[bi][ch0 * 8], 16, 0, 0);
        __builtin_amdgcn_global_load_lds((const GLOBAL_AS void*)(Bt + (size_t)(n0 + r1) * K + k0 + g1),
                                         (LDS_AS void*)&sB[bi][ch1 * 8], 16, 0, 0);
    };

    stage(0);
    stage(1);
    for (int kt = 0; kt < KT; ++kt) {
        if (kt + 2 < KT) {
            stage(kt + 2);
            // 12 loads may be outstanding; keep the 8 newest (tiles kt+1, kt+2) in flight.
            asm volatile("s_waitcnt vmcnt(8)" ::: "memory");
        } else if (kt + 2 == KT) {
            asm volatile("s_waitcnt vmcnt(4)" ::: "memory");
        } else {
            asm volatile("s_waitcnt vmcnt(0)" ::: "memory");
        }
        __builtin_amdgcn_s_barrier();  // buf[kt%3] ready for all waves
        int bi = kt % 3;
        bf16x8 af[4], bfr[4];
#pragma unroll
        for (int mi = 0; mi < 4; ++mi)
            af[mi] = *(const bf16x8*)&sA[bi][(wm + mi * 16 + lr) * 32 + qx];
#pragma unroll
        for (int ni = 0; ni < 4; ++ni)
            bfr[ni] = *(const bf16x8*)&sB[bi][(wn + ni * 16 + lr) * 32 + qx];
#pragma unroll
        for (int mi = 0; mi < 4; ++mi)
#pragma unroll
            for (int ni = 0; ni < 4; ++ni)
                acc[mi][ni] = __builtin_amdgcn_mfma_f32_16x16x32_bf16(bfr[ni], af[mi], acc[mi][ni], 0, 0, 0);
        // All ds_reads of buf[kt%3] must land before any wave's stage(kt+3) overwrites it.
        asm volatile("s_waitcnt lgkmcnt(0)" ::: "memory");
        __builtin_amdgcn_s_barrier();
    }

    // epilogue: row = m0+wm+mi*16+lr, cols = n0+wn+ni*16+quad*4 .. +3 (plain stores; L2 merges)
#pragma unroll
    for (int mi = 0; mi < 4; ++mi) {
        int row = m0 + wm + mi * 16 + lr;
#pragma unroll
        for (int ni = 0; ni < 4; ++ni) {
            int col = n0 + wn + ni * 16 + quad * 4;
            size_t idx = (size_t)row * N + col;
            f32x4 v = acc[mi][ni];
            if (bias) {
                const float4 b4 = *(const float4*)&bias[col];
                v[0] += b4.x; v[1] += b4.y; v[2] += b4.z; v[3] += b4.w;
            }
            if (act == 1) {
#pragma unroll
                for (int e = 0; e < 4; ++e) {
                    // tanh-approx gelu (max dev ~3e-4 vs exact; vanishes through next GEMM)
                    float xv = v[e];
                    float u = 0.7978845608f * (xv + 0.044715f * xv * xv * xv);
                    float ex = __expf(2.f * u);
                    float th = (ex - 1.f) / (ex + 1.f);
                    v[e] = 0.5f * xv * (1.f + th);
                }
            }
            if (add) {
                const float4 a4 = *(const float4*)&add[idx];
                v[0] += a4.x; v[1] += a4.y; v[2] += a4.z; v[3] += a4.w;
            }
            if (outH) {
                union { __hip_bfloat16 h[4]; int2 i2; } u;
                u.h[0] = __float2bfloat16(v[0]);
                u.h[1] = __float2bfloat16(v[1]);
                u.h[2] = __float2bfloat16(v[2]);
                u.h[3] = __float2bfloat16(v[3]);
                *(int2*)&outH[idx] = u.i2;
            } else {
                *(float4*)&outF[idx] = make_float4(v[0], v[1], v[2], v[3]);
            }
        }
    }
}

extern "C" void kernel_launch(void* const* d_in, const int* in_sizes, int n_in,
                              void* d_out, int out_size, void* d_ws, size_t ws_size,
                              hipStream_t stream) {
    const float* x = (const float*)d_in[0];
    const float* gamma1 = (const float*)d_in[1];
    const float* beta1 = (const float*)d_in[2];
    const float* dwc_w = (const float*)d_in[3];
    const float* dwc_b = (const float*)d_in[4];
    const float* gru1_w = (const float*)d_in[5];
    const float* gru1_o = (const float*)d_in[6];
    const float* gru2_w = (const float*)d_in[7];
    const float* gru2_o = (const float*)d_in[8];
    const float* gamma2 = (const float*)d_in[9];
    const float* beta2 = (const float*)d_in[10];
    const float* p1_w = (const float*)d_in[11];
    const float* p1_b = (const float*)d_in[12];
    const float* p2_w = (const float*)d_in[13];
    const float* p2_b = (const float*)d_in[14];
    float* out = (float*)d_out;

    char* ws = (char*)d_ws;
    size_t off = 0;
    auto alloc = [&](size_t b) {
        char* p = ws + off;
        off += (b + 255) & ~(size_t)255;
        return p;
    };
    const size_t M = M_ROWS;
    // ws total ~188 MB
    __hip_bfloat16* hg = (__hip_bfloat16*)alloc(M * 2 * DI * 2);    // 100.7 MB; h2 in-place; later t1
    __hip_bfloat16* hbuf = (__hip_bfloat16*)alloc(M * DI * 2);      // 50.3 MB: LN1-bf16 out, then h1
    __hip_bfloat16* xs = (__hip_bfloat16*)alloc(M * DIM * 2);       // 25.2 MB; later yn
    float* summ = (float*)alloc((size_t)2 * CHUNKS * NB * DI * 4);  // 6.3 MB
    __hip_bfloat16* w1T = (__hip_bfloat16*)alloc((size_t)DIM * 2 * DI * 2);
    __hip_bfloat16* w2T = (__hip_bfloat16*)alloc((size_t)DIM * 2 * DI * 2);
    __hip_bfloat16* ocT = (__hip_bfloat16*)alloc((size_t)DIM * 2 * DI * 2);  // 384 x 1536 = [o1;o2]^T
    __hip_bfloat16* p1T = (__hip_bfloat16*)alloc((size_t)DIM * MLP_DIM * 2);
    __hip_bfloat16* p2T = (__hip_bfloat16*)alloc((size_t)MLP_DIM * DIM * 2);
    __hip_bfloat16* xnb = hbuf;           // LN1 out (bf16); dead after dwconv, before scan1
    float* y = (float*)d_out;             // post-GRU residual; same-idx RMW only
    __hip_bfloat16* yn = xs;              // LN2 out; xs dead after GRU2 input GEMM
    __hip_bfloat16* t1 = hg;              // MLP hidden; hg dead after scan2

    auto tgrid = [](int n) { return dim3((n + 255) / 256); };
    transpose_bf16_kernel<<<tgrid(DIM * 2 * DI), 256, 0, stream>>>(gru1_w, w1T, DIM, 2 * DI, DIM, 0);
    transpose_bf16_kernel<<<tgrid(DIM * 2 * DI), 256, 0, stream>>>(gru2_w, w2T, DIM, 2 * DI, DIM, 0);
    transpose_bf16_kernel<<<tgrid(DI * DIM), 256, 0, stream>>>(gru1_o, ocT, DI, DIM, 2 * DI, 0);
    transpose_bf16_kernel<<<tgrid(DI * DIM), 256, 0, stream>>>(gru2_o, ocT, DI, DIM, 2 * DI, DI);
    transpose_bf16_kernel<<<tgrid(DIM * MLP_DIM), 256, 0, stream>>>(p1_w, p1T, DIM, MLP_DIM, DIM, 0);
    transpose_bf16_kernel<<<tgrid(MLP_DIM * DIM), 256, 0, stream>>>(p2_w, p2T, MLP_DIM, DIM, MLP_DIM, 0);

    ln_kernel<__hip_bfloat16><<<dim3(M / 4), 256, 0, stream>>>(x, gamma1, beta1, xnb);
    dwconv_kernel<<<dim3((int)((M * DIM / 8) / 256)), 256, 0, stream>>>(xnb, dwc_w, dwc_b, xs);

    const int scan_blocks = NB * CHUNKS * DI / 256;  // 3072
    // GRU1: hg = xs @ w1; scan fwd -> h1 (hbuf, stride DI)
    gemm_bt<<<dim3(2 * DI / 128, M / 128), 256, 0, stream>>>(xs, DIM, xs, DIM, DIM, w1T, M, 2 * DI, DIM,
                                                             hg, nullptr, nullptr, nullptr, 0);
    scan_part1<<<dim3(scan_blocks), 256, 0, stream>>>(hg, summ, 0);
    scan_part2<<<dim3(scan_blocks), 256, 0, stream>>>(hg, summ, hbuf, 0, DI);
    // GRU2: hg = xs @ w2; scan bwd -> h2 in-place into hg[:, 0:DI] (stride 2*DI)
    gemm_bt<<<dim3(2 * DI / 128, M / 128), 256, 0, stream>>>(xs, DIM, xs, DIM, DIM, w2T, M, 2 * DI, DIM,
                                                             hg, nullptr, nullptr, nullptr, 0);
    scan_part1<<<dim3(scan_blocks), 256, 0, stream>>>(hg, summ, 1);
    scan_part2<<<dim3(scan_blocks), 256, 0, stream>>>(hg, summ, hg, 1, 2 * DI);

    // merged GRU out: y = [h1 | h2] @ [o1;o2] + x   (K=1536)
    gemm_bt<<<dim3(DIM / 128, M / 128), 256, 0, stream>>>(hbuf, DI, hg, 2 * DI, DI, ocT, M, DIM, 2 * DI,
                                                          nullptr, y, nullptr, x, 0);

    // LN2 + MLP
    ln_kernel<__hip_bfloat16><<<dim3(M / 4), 256, 0, stream>>>(y, gamma2, beta2, yn);
    gemm_bt<<<dim3(MLP_DIM / 128, M / 128), 256, 0, stream>>>(yn, DIM, yn, DIM, DIM, p1T, M, MLP_DIM, DIM,
                                                              t1, nullptr, p1_b, nullptr, 1);
    gemm_bt<<<dim3(DIM / 128, M / 128), 256, 0, stream>>>(t1, MLP_DIM, t1, MLP_DIM, MLP_DIM, p2T, M, DIM, MLP_DIM,
                                                          nullptr, out, p2_b, y, 0);
}

// Round 4
// 693.856 us; speedup vs baseline: 1.2136x; 1.0297x over previous
//
#include <hip/hip_runtime.h>
#include <hip/hip_bf16.h>

#define DIM 384
#define DI 768
#define S_LEN 1024
#define NB 32
#define M_ROWS (NB * S_LEN)   // 32768
#define MLP_DIM 1536
#define CHUNKS 32
#define CLEN (S_LEN / CHUNKS)  // 32

typedef __bf16 bf16x8 __attribute__((ext_vector_type(8)));
typedef float f32x4 __attribute__((ext_vector_type(4)));

#define GLOBAL_AS __attribute__((address_space(1)))
#define LDS_AS __attribute__((address_space(3)))

// ---------------- LayerNorm: one wave per row of 384 ----------------
template <typename OutT>
__global__ __launch_bounds__(256) void ln_kernel(const float* __restrict__ x,
                                                 const float* __restrict__ gamma,
                                                 const float* __restrict__ beta,
                                                 OutT* __restrict__ out) {
    int row = blockIdx.x * 4 + (threadIdx.x >> 6);
    int lane = threadIdx.x & 63;
    const float* xr = x + (size_t)row * DIM;
    float v[6];
    float s = 0.f, sq = 0.f;
#pragma unroll
    for (int i = 0; i < 6; ++i) {
        v[i] = xr[lane + i * 64];
        s += v[i];
        sq += v[i] * v[i];
    }
#pragma unroll
    for (int off = 32; off > 0; off >>= 1) {
        s += __shfl_down(s, off);
        sq += __shfl_down(sq, off);
    }
    s = __shfl(s, 0);
    sq = __shfl(sq, 0);
    float mean = s * (1.f / DIM);
    float var = sq * (1.f / DIM) - mean * mean;
    float rstd = rsqrtf(var + 1e-5f);
    OutT* orow = out + (size_t)row * DIM;
#pragma unroll
    for (int i = 0; i < 6; ++i) {
        int c = lane + i * 64;
        float y = (v[i] - mean) * rstd * gamma[c] + beta[c];
        if constexpr (sizeof(OutT) == 2)
            orow[c] = __float2bfloat16(y);
        else
            orow[c] = y;
    }
}

// ------- Depthwise 3x3 conv, vectorized: each thread does 8 consecutive channels -------
// xn channel-last [n][s][c] bf16; taps are bf16x8 16B loads; weights (c*9 contiguous
// floats) hoisted to registers via float4 loads (L1-resident, 13.8 KB total).
__global__ __launch_bounds__(256) void dwconv_kernel(const __hip_bfloat16* __restrict__ xn,
                                                     const float* __restrict__ w,
                                                     const float* __restrict__ b,
                                                     __hip_bfloat16* __restrict__ xs) {
    const int CB = DIM / 8;  // 48 channel-blocks per position
    size_t tid = (size_t)blockIdx.x * 256 + threadIdx.x;
    int cb = (int)(tid % CB);
    int s = (int)((tid / CB) % S_LEN);
    int n = (int)(tid / ((size_t)CB * S_LEN));
    int c = cb * 8;
    int h0 = s >> 5, w0 = s & 31;

    // weights: w[c*9 .. c*9+71] contiguous, 16B-aligned (c%8==0 -> c*36 bytes % 16 == 0)
    float wv[72];
    {
        const float4* wp = (const float4*)(w + (size_t)c * 9);
#pragma unroll
        for (int i = 0; i < 18; ++i) ((float4*)wv)[i] = wp[i];
    }
    float acc[8];
    {
        const float4 b0 = *(const float4*)&b[c];
        const float4 b1 = *(const float4*)&b[c + 4];
        acc[0] = b0.x; acc[1] = b0.y; acc[2] = b0.z; acc[3] = b0.w;
        acc[4] = b1.x; acc[5] = b1.y; acc[6] = b1.z; acc[7] = b1.w;
    }

    const __hip_bfloat16* base = xn + (size_t)n * S_LEN * DIM + c;
#pragma unroll
    for (int kh = 0; kh < 3; ++kh) {
        int hh = h0 + kh - 1;
        if (hh < 0 || hh > 31) continue;
#pragma unroll
        for (int kw = 0; kw < 3; ++kw) {
            int ww = w0 + kw - 1;
            if (ww < 0 || ww > 31) continue;
            bf16x8 xv = *(const bf16x8*)&base[(size_t)(hh * 32 + ww) * DIM];
#pragma unroll
            for (int e = 0; e < 8; ++e)
                acc[e] += (float)xv[e] * wv[e * 9 + kh * 3 + kw];
        }
    }
    bf16x8 ov;
#pragma unroll
    for (int e = 0; e < 8; ++e) ov[e] = (__bf16)acc[e];
    *(bf16x8*)&xs[tid * 8] = ov;
}

// ------- transpose + cast f32 -> bf16: out[c*ostride + ooff + r] = in[r*C + c] -------
__global__ __launch_bounds__(256) void transpose_bf16_kernel(const float* __restrict__ in,
                                                             __hip_bfloat16* __restrict__ out,
                                                             int R, int C, int ostride, int ooff) {
    int idx = blockIdx.x * 256 + threadIdx.x;
    if (idx >= R * C) return;
    int r = idx / C, c = idx % C;
    out[(size_t)c * ostride + ooff + r] = __float2bfloat16(in[idx]);
}

// ---------------- minGRU chunked scan ----------------
__device__ __forceinline__ void gru_ab(float hid, float gate, float& a, float& bv) {
    float z = 1.f / (1.f + __expf(-gate));
    float gh = (hid >= 0.f) ? (hid + 0.5f) : (1.f / (1.f + __expf(-hid)));
    a = 1.f - z;
    bv = z * gh;
}

__global__ __launch_bounds__(256) void scan_part1(const __hip_bfloat16* __restrict__ hg,
                                                  float* __restrict__ summ, int rev) {
    int tid = blockIdx.x * 256 + threadIdx.x;  // NB*CHUNKS*DI
    int c = tid % DI;
    int j = (tid / DI) % CHUNKS;
    int b = tid / (DI * CHUNKS);
    const __hip_bfloat16* base = hg + (size_t)b * S_LEN * (2 * DI);
    float A = 1.f, Bv = 0.f;
    for (int i = 0; i < CLEN; i += 8) {
        float hid[8], gate[8];
#pragma unroll
        for (int q = 0; q < 8; ++q) {
            int pos = j * CLEN + i + q;
            int t = rev ? (S_LEN - 1 - pos) : pos;
            hid[q] = __bfloat162float(base[(size_t)t * (2 * DI) + c]);
            gate[q] = __bfloat162float(base[(size_t)t * (2 * DI) + DI + c]);
        }
#pragma unroll
        for (int q = 0; q < 8; ++q) {
            float a, bv;
            gru_ab(hid[q], gate[q], a, bv);
            A *= a;
            Bv = a * Bv + bv;
        }
    }
    int idx = (j * NB + b) * DI + c;
    summ[idx] = A;
    summ[(size_t)CHUNKS * NB * DI + idx] = Bv;
}

// part2: writes h with row stride `ostride`; may alias hg in-place (1:1 read-before-write)
__global__ __launch_bounds__(256) void scan_part2(const __hip_bfloat16* __restrict__ hg,
                                                  const float* __restrict__ summ,
                                                  __hip_bfloat16* __restrict__ ho, int rev,
                                                  int ostride) {
    int tid = blockIdx.x * 256 + threadIdx.x;
    int c = tid % DI;
    int j = (tid / DI) % CHUNKS;
    int b = tid / (DI * CHUNKS);
    const float* sB = summ + (size_t)CHUNKS * NB * DI;
    float h = 0.f;
    for (int jp = 0; jp < j; ++jp) {
        int idx = (jp * NB + b) * DI + c;
        h = summ[idx] * h + sB[idx];
    }
    const __hip_bfloat16* base = hg + (size_t)b * S_LEN * (2 * DI);
    __hip_bfloat16* hob = ho + (size_t)b * S_LEN * ostride;
    for (int i = 0; i < CLEN; i += 8) {
        float hid[8], gate[8];
        int tt[8];
#pragma unroll
        for (int q = 0; q < 8; ++q) {
            int pos = j * CLEN + i + q;
            int t = rev ? (S_LEN - 1 - pos) : pos;
            tt[q] = t;
            hid[q] = __bfloat162float(base[(size_t)t * (2 * DI) + c]);
            gate[q] = __bfloat162float(base[(size_t)t * (2 * DI) + DI + c]);
        }
#pragma unroll
        for (int q = 0; q < 8; ++q) {
            float a, bv;
            gru_ab(hid[q], gate[q], a, bv);
            h = a * h + bv;
            hob[(size_t)tt[q] * ostride + c] = __float2bfloat16(h);
        }
    }
}

// ------- bf16 MFMA GEMM: dual-A (k-split), global_load_lds staging, depth-2 prefetch -------
// out = [A1|A2](MxK) @ B(KxN); Bt is N x K. MFMA as (b,a): lane -> row m (lr), 4 consecutive cols.
//
// SINGLE-barrier K-loop (round 3): iter kt = [vmcnt(4); barrier; ds_read buf[kt%3];
// stage(kt+2); MFMA]. WAR safety: stage(kt+2) overwrites buf[(kt-1)%3]; a wave reaches
// BARRIER_kt only after its MFMAs of iter kt-1 executed (lgkm drained => its buf[kt-1]
// reads complete), so barrier release => ALL waves' buf[kt-1] reads complete, and the
// post-barrier stage is safe. RAW: vmcnt(4) retires tile kt's 4 loads (tile kt+1 stays
// in flight across the barrier - counted, never 0 mid-loop). Removes the per-iter
// lgkmcnt(0) drain + second barrier of the round-0 schedule.
//
// XCD-chunked tile swizzle: blocks sharing an A-panel land on one XCD's L2 (all grids %8==0).
// T2 LDS swizzle (G21 both-sides): rows are 64B (4x 16B slots); unswizzled, a 16-lane ds_read
// group is 8-way bank-conflicted. LDS[row][s] = global[row][s ^ f(row)], f(row)=(row>>1)&3,
// applied on the *global source* slot in stage (global_load_lds dest stays linear); read with
// quad ^ f(row) (loop-invariant, reduces to (lr>>1)&3). Verified: SQ_LDS_BANK_CONFLICT = 0.
__global__ __launch_bounds__(256) void gemm_bt(const __hip_bfloat16* __restrict__ A1, int lda1,
                                               const __hip_bfloat16* __restrict__ A2, int lda2,
                                               int ksplit,
                                               const __hip_bfloat16* __restrict__ Bt,
                                               int M, int N, int K,
                                               __hip_bfloat16* __restrict__ outH,
                                               float* __restrict__ outF,
                                               const float* __restrict__ bias,
                                               const float* __restrict__ add,
                                               int act) {
    __shared__ __align__(16) __hip_bfloat16 sA[3][128 * 32];
    __shared__ __align__(16) __hip_bfloat16 sB[3][128 * 32];
    int t = threadIdx.x;

    // XCD swizzle: hardware round-robins consecutive block ids across 8 XCDs; remap so each
    // XCD processes a contiguous chunk of tiles (contiguous M-panels -> A panel fits its L2).
    int nwg = gridDim.x * gridDim.y;
    int bid = blockIdx.y * gridDim.x + blockIdx.x;
    int cpx = nwg >> 3;  // all gemm grids here are divisible by 8 (bijective)
    int tile = (bid & 7) * cpx + (bid >> 3);
    int bx = tile % gridDim.x;
    int by = tile / gridDim.x;
    int n0 = bx * 128;
    int m0 = by * 128;

    int wave = t >> 6, lane = t & 63;
    int wm = (wave >> 1) << 6, wn = (wave & 1) << 6;
    int quad = lane >> 4, lr = lane & 15;

    f32x4 acc[4][4];
#pragma unroll
    for (int i = 0; i < 4; ++i)
#pragma unroll
        for (int j = 0; j < 4; ++j)
#pragma unroll
            for (int e = 0; e < 4; ++e) acc[i][j][e] = 0.f;

    int ch0 = wave * 128 + lane;
    int ch1 = wave * 128 + 64 + lane;
    // stage-side swizzle: thread covering LDS (row r, slot s=ch&3) fetches global slot s^f(r)
    int r0 = ch0 >> 2, g0 = (((ch0 & 3) ^ ((r0 >> 1) & 3)) * 8);
    int r1 = ch1 >> 2, g1 = (((ch1 & 3) ^ ((r1 >> 1) & 3)) * 8);
    // read-side swizzle offset (loop-invariant): element offset (quad ^ (lr>>1)&3)*8
    int qx = (quad ^ ((lr >> 1) & 3)) * 8;

    const int KT = K >> 5;  // #32-wide k-tiles (>= 12 for all calls)

    auto stage = [&](int kt) {
        int k0 = kt << 5;
        const __hip_bfloat16* Ab;
        int ldx, kk;
        if (k0 < ksplit) { Ab = A1; ldx = lda1; kk = k0; }
        else             { Ab = A2; ldx = lda2; kk = k0 - ksplit; }
        int bi = kt % 3;
        __builtin_amdgcn_global_load_lds((const GLOBAL_AS void*)(Ab + (size_t)(m0 + r0) * ldx + kk + g0),
                                         (LDS_AS void*)&sA[bi][ch0 * 8], 16, 0, 0);
        __builtin_amdgcn_global_load_lds((const GLOBAL_AS void*)(Ab + (size_t)(m0 + r1) * ldx + kk + g1),
                                         (LDS_AS void*)&sA[bi][ch1 * 8], 16, 0, 0);
        __builtin_amdgcn_global_load_lds((const GLOBAL_AS void*)(Bt + (size_t)(n0 + r0) * K + k0 + g0),
                                         (LDS_AS void*)&sB[bi][ch0 * 8], 16, 0, 0);
        __builtin_amdgcn_global_load_lds((const GLOBAL_AS void*)(Bt + (size_t)(n0 + r1) * K + k0 + g1),
                                         (LDS_AS void*)&sB[bi][ch1 * 8], 16, 0, 0);
    };

    stage(0);
    stage(1);
    for (int kt = 0; kt < KT; ++kt) {
        // Retire tile kt's loads (keep tile kt+1 in flight - counted vmcnt, never 0 mid-loop).
        if (kt + 1 < KT) {
            asm volatile("s_waitcnt vmcnt(4)" ::: "memory");
        } else {
            asm volatile("s_waitcnt vmcnt(0)" ::: "memory");
        }
        __builtin_amdgcn_s_barrier();  // buf[kt%3] ready; all buf[kt-1] reads drained
        asm volatile("" ::: "memory"); // pin: no memory op (stage) hoists above the barrier
        int bi = kt % 3;
        bf16x8 af[4], bfr[4];
#pragma unroll
        for (int mi = 0; mi < 4; ++mi)
            af[mi] = *(const bf16x8*)&sA[bi][(wm + mi * 16 + lr) * 32 + qx];
#pragma unroll
        for (int ni = 0; ni < 4; ++ni)
            bfr[ni] = *(const bf16x8*)&sB[bi][(wn + ni * 16 + lr) * 32 + qx];
        if (kt + 2 < KT) stage(kt + 2);  // issue under the lgkm shadow of the ds_reads
#pragma unroll
        for (int mi = 0; mi < 4; ++mi)
#pragma unroll
            for (int ni = 0; ni < 4; ++ni)
                acc[mi][ni] = __builtin_amdgcn_mfma_f32_16x16x32_bf16(bfr[ni], af[mi], acc[mi][ni], 0, 0, 0);
    }

    // epilogue: row = m0+wm+mi*16+lr, cols = n0+wn+ni*16+quad*4 .. +3 (plain stores; L2 merges)
#pragma unroll
    for (int mi = 0; mi < 4; ++mi) {
        int row = m0 + wm + mi * 16 + lr;
#pragma unroll
        for (int ni = 0; ni < 4; ++ni) {
            int col = n0 + wn + ni * 16 + quad * 4;
            size_t idx = (size_t)row * N + col;
            f32x4 v = acc[mi][ni];
            if (bias) {
                const float4 b4 = *(const float4*)&bias[col];
                v[0] += b4.x; v[1] += b4.y; v[2] += b4.z; v[3] += b4.w;
            }
            if (act == 1) {
#pragma unroll
                for (int e = 0; e < 4; ++e) {
                    // tanh-approx gelu (max dev ~3e-4 vs exact; vanishes through next GEMM)
                    float xv = v[e];
                    float u = 0.7978845608f * (xv + 0.044715f * xv * xv * xv);
                    float ex = __expf(2.f * u);
                    float th = (ex - 1.f) / (ex + 1.f);
                    v[e] = 0.5f * xv * (1.f + th);
                }
            }
            if (add) {
                const float4 a4 = *(const float4*)&add[idx];
                v[0] += a4.x; v[1] += a4.y; v[2] += a4.z; v[3] += a4.w;
            }
            if (outH) {
                union { __hip_bfloat16 h[4]; int2 i2; } u;
                u.h[0] = __float2bfloat16(v[0]);
                u.h[1] = __float2bfloat16(v[1]);
                u.h[2] = __float2bfloat16(v[2]);
                u.h[3] = __float2bfloat16(v[3]);
                *(int2*)&outH[idx] = u.i2;
            } else {
                *(float4*)&outF[idx] = make_float4(v[0], v[1], v[2], v[3]);
            }
        }
    }
}

extern "C" void kernel_launch(void* const* d_in, const int* in_sizes, int n_in,
                              void* d_out, int out_size, void* d_ws, size_t ws_size,
                              hipStream_t stream) {
    const float* x = (const float*)d_in[0];
    const float* gamma1 = (const float*)d_in[1];
    const float* beta1 = (const float*)d_in[2];
    const float* dwc_w = (const float*)d_in[3];
    const float* dwc_b = (const float*)d_in[4];
    const float* gru1_w = (const float*)d_in[5];
    const float* gru1_o = (const float*)d_in[6];
    const float* gru2_w = (const float*)d_in[7];
    const float* gru2_o = (const float*)d_in[8];
    const float* gamma2 = (const float*)d_in[9];
    const float* beta2 = (const float*)d_in[10];
    const float* p1_w = (const float*)d_in[11];
    const float* p1_b = (const float*)d_in[12];
    const float* p2_w = (const float*)d_in[13];
    const float* p2_b = (const float*)d_in[14];
    float* out = (float*)d_out;

    char* ws = (char*)d_ws;
    size_t off = 0;
    auto alloc = [&](size_t b) {
        char* p = ws + off;
        off += (b + 255) & ~(size_t)255;
        return p;
    };
    const size_t M = M_ROWS;
    // ws total ~188 MB
    __hip_bfloat16* hg = (__hip_bfloat16*)alloc(M * 2 * DI * 2);    // 100.7 MB; h2 in-place; later t1
    __hip_bfloat16* hbuf = (__hip_bfloat16*)alloc(M * DI * 2);      // 50.3 MB: LN1-bf16 out, then h1
    __hip_bfloat16* xs = (__hip_bfloat16*)alloc(M * DIM * 2);       // 25.2 MB; later yn
    float* summ = (float*)alloc((size_t)2 * CHUNKS * NB * DI * 4);  // 6.3 MB
    __hip_bfloat16* w1T = (__hip_bfloat16*)alloc((size_t)DIM * 2 * DI * 2);
    __hip_bfloat16* w2T = (__hip_bfloat16*)alloc((size_t)DIM * 2 * DI * 2);
    __hip_bfloat16* ocT = (__hip_bfloat16*)alloc((size_t)DIM * 2 * DI * 2);  // 384 x 1536 = [o1;o2]^T
    __hip_bfloat16* p1T = (__hip_bfloat16*)alloc((size_t)DIM * MLP_DIM * 2);
    __hip_bfloat16* p2T = (__hip_bfloat16*)alloc((size_t)MLP_DIM * DIM * 2);
    __hip_bfloat16* xnb = hbuf;           // LN1 out (bf16); dead after dwconv, before scan1
    float* y = (float*)d_out;             // post-GRU residual; same-idx RMW only
    __hip_bfloat16* yn = xs;              // LN2 out; xs dead after GRU2 input GEMM
    __hip_bfloat16* t1 = hg;              // MLP hidden; hg dead after scan2

    auto tgrid = [](int n) { return dim3((n + 255) / 256); };
    transpose_bf16_kernel<<<tgrid(DIM * 2 * DI), 256, 0, stream>>>(gru1_w, w1T, DIM, 2 * DI, DIM, 0);
    transpose_bf16_kernel<<<tgrid(DIM * 2 * DI), 256, 0, stream>>>(gru2_w, w2T, DIM, 2 * DI, DIM, 0);
    transpose_bf16_kernel<<<tgrid(DI * DIM), 256, 0, stream>>>(gru1_o, ocT, DI, DIM, 2 * DI, 0);
    transpose_bf16_kernel<<<tgrid(DI * DIM), 256, 0, stream>>>(gru2_o, ocT, DI, DIM, 2 * DI, DI);
    transpose_bf16_kernel<<<tgrid(DIM * MLP_DIM), 256, 0, stream>>>(p1_w, p1T, DIM, MLP_DIM, DIM, 0);
    transpose_bf16_kernel<<<tgrid(MLP_DIM * DIM), 256, 0, stream>>>(p2_w, p2T, MLP_DIM, DIM, MLP_DIM, 0);

    ln_kernel<__hip_bfloat16><<<dim3(M / 4), 256, 0, stream>>>(x, gamma1, beta1, xnb);
    dwconv_kernel<<<dim3((int)((M * DIM / 8) / 256)), 256, 0, stream>>>(xnb, dwc_w, dwc_b, xs);

    const int scan_blocks = NB * CHUNKS * DI / 256;  // 3072
    // GRU1: hg = xs @ w1; scan fwd -> h1 (hbuf, stride DI)
    gemm_bt<<<dim3(2 * DI / 128, M / 128), 256, 0, stream>>>(xs, DIM, xs, DIM, DIM, w1T, M, 2 * DI, DIM,
                                                             hg, nullptr, nullptr, nullptr, 0);
    scan_part1<<<dim3(scan_blocks), 256, 0, stream>>>(hg, summ, 0);
    scan_part2<<<dim3(scan_blocks), 256, 0, stream>>>(hg, summ, hbuf, 0, DI);
    // GRU2: hg = xs @ w2; scan bwd -> h2 in-place into hg[:, 0:DI] (stride 2*DI)
    gemm_bt<<<dim3(2 * DI / 128, M / 128), 256, 0, stream>>>(xs, DIM, xs, DIM, DIM, w2T, M, 2 * DI, DIM,
                                                             hg, nullptr, nullptr, nullptr, 0);
    scan_part1<<<dim3(scan_blocks), 256, 0, stream>>>(hg, summ, 1);
    scan_part2<<<dim3(scan_blocks), 256, 0, stream>>>(hg, summ, hg, 1, 2 * DI);

    // merged GRU out: y = [h1 | h2] @ [o1;o2] + x   (K=1536)
    gemm_bt<<<dim3(DIM / 128, M / 128), 256, 0, stream>>>(hbuf, DI, hg, 2 * DI, DI, ocT, M, DIM, 2 * DI,
                                                          nullptr, y, nullptr, x, 0);

    // LN2 + MLP
    ln_kernel<__hip_bfloat16><<<dim3(M / 4), 256, 0, stream>>>(y, gamma2, beta2, yn);
    gemm_bt<<<dim3(MLP_DIM / 128, M / 128), 256, 0, stream>>>(yn, DIM, yn, DIM, DIM, p1T, M, MLP_DIM, DIM,
                                                              t1, nullptr, p1_b, nullptr, 1);
    gemm_bt<<<dim3(DIM / 128, M / 128), 256, 0, stream>>>(t1, MLP_DIM, t1, MLP_DIM, MLP_DIM, p2T, M, DIM, MLP_DIM,
                                                          nullptr, out, p2_b, y, 0);
}